// Round 9
// baseline (450.500 us; speedup 1.0000x reference)
//
#include <hip/hip_runtime.h>
#include <hip/hip_bf16.h>
#include <stdint.h>

#define B_SZ 8192
#define D_SZ 1024
#define O_SZ 1024
#define E_SZ 8

#define BM 256
#define BN 128
#define BK 64
#define NT 128  // virtual K-steps: E_SZ * (D_SZ / BK)

typedef __bf16 bf16_t;
typedef __bf16 bf16x8 __attribute__((ext_vector_type(8)));
typedef __bf16 bf16x4 __attribute__((ext_vector_type(4)));
typedef float  f32x4  __attribute__((ext_vector_type(4)));

// ---------------- merged prep: gating+cvt (blocks 0..2047) | We transpose (2048..4095) ----------------
__global__ __launch_bounds__(256) void prep_kernel(
    const float* __restrict__ x, const float* __restrict__ Wg,
    const float* __restrict__ bg, const float* __restrict__ We,
    float* __restrict__ gates, bf16_t* __restrict__ xb,
    bf16_t* __restrict__ wet) {
  __shared__ float tile[64][65];
  const int bid = blockIdx.x;
  if (bid < 2048) {
    // ---- gating: softmax(x @ Wg + bg) fused with x fp32->bf16 ----
    const int w = threadIdx.x >> 6, lane = threadIdx.x & 63;
    const int b = bid * 4 + w;
    const float4* xr = (const float4*)(x + (size_t)b * D_SZ);
    bf16x4* xbr = (bf16x4*)(xb + (size_t)b * D_SZ);
    float acc[8];
#pragma unroll
    for (int e = 0; e < 8; ++e) acc[e] = 0.f;
#pragma unroll 1
    for (int it = 0; it < 4; ++it) {
      int d4 = it * 64 + lane;  // float4 index; d = d4*4
      float4 v = xr[d4];
      bf16x4 ob;
      ob[0] = (bf16_t)v.x; ob[1] = (bf16_t)v.y;
      ob[2] = (bf16_t)v.z; ob[3] = (bf16_t)v.w;
      xbr[d4] = ob;
      const float4* wr = (const float4*)(Wg + (size_t)d4 * 32);  // 4 rows x 8
      float xs[4] = {v.x, v.y, v.z, v.w};
#pragma unroll
      for (int rr = 0; rr < 4; ++rr) {
        float4 wa = wr[rr * 2], wb = wr[rr * 2 + 1];
        acc[0] += xs[rr] * wa.x; acc[1] += xs[rr] * wa.y;
        acc[2] += xs[rr] * wa.z; acc[3] += xs[rr] * wa.w;
        acc[4] += xs[rr] * wb.x; acc[5] += xs[rr] * wb.y;
        acc[6] += xs[rr] * wb.z; acc[7] += xs[rr] * wb.w;
      }
    }
#pragma unroll
    for (int off = 32; off >= 1; off >>= 1) {
#pragma unroll
      for (int e = 0; e < 8; ++e) acc[e] += __shfl_xor(acc[e], off, 64);
    }
    if (lane == 0) {
#pragma unroll
      for (int e = 0; e < 8; ++e) acc[e] += bg[e];
      float m = acc[0];
#pragma unroll
      for (int e = 1; e < 8; ++e) m = fmaxf(m, acc[e]);
      float s = 0.f, ex[8];
#pragma unroll
      for (int e = 0; e < 8; ++e) { ex[e] = __expf(acc[e] - m); s += ex[e]; }
      float inv = 1.0f / s;
      float* gr = gates + (size_t)b * 8;
#pragma unroll
      for (int e = 0; e < 8; ++e) gr[e] = ex[e] * inv;
    }
  } else {
    // ---- We [E,D,O] fp32 -> WeT [E,O,D] bf16 ----
    const int bt = bid - 2048;
    const int e = bt >> 8;
    const int d0 = ((bt >> 4) & 15) * 64, o0 = (bt & 15) * 64;
    const int tx = threadIdx.x & 63, ty = threadIdx.x >> 6;
    const float* src = We + (size_t)e * D_SZ * O_SZ;
#pragma unroll
    for (int i = 0; i < 16; ++i) {
      int d = ty + i * 4;
      tile[d][tx] = src[(size_t)(d0 + d) * O_SZ + o0 + tx];
    }
    __syncthreads();
    bf16_t* dst = wet + (size_t)e * O_SZ * D_SZ;
#pragma unroll
    for (int i = 0; i < 16; ++i) {
      int o = ty + i * 4;
      dst[(size_t)(o0 + o) * D_SZ + d0 + tx] = (bf16_t)tile[tx][o];
    }
  }
}

// ---------------- fused expert GEMM + gate combine (R3 + parity stagger) ----------------
// R3 proven structure (ring-3 LDS for A and B, counted vmcnt(6), XOR swizzle,
// hoisted LDS offsets, setprio) + ONE change: odd waves execute the two
// k-half phases in reverse order, so at any instant ~half the waves feed the
// LDS port while half feed the MFMA pipe (R3 was lockstep: step =
// 1536 read-burst + 1242 MFMA + 90 = 2868 cyc, a SUM not a MAX).
__device__ __forceinline__ void gl16(const bf16_t* g, const bf16_t* l) {
  __builtin_amdgcn_global_load_lds(
      (const __attribute__((address_space(1))) void*)g,
      (__attribute__((address_space(3))) void*)l, 16, 0, 0);
}

__global__ __launch_bounds__(512, 2) void moe_gemm(
    const bf16_t* __restrict__ xb,    // [B, D] bf16
    const bf16_t* __restrict__ wet,   // [E, O, D] bf16
    const float* __restrict__ gates,  // [B, E]
    const float* __restrict__ be,     // [E, O]
    float* __restrict__ out)          // [B, O]
{
  // ring-3 buffers: compute t from buf t%3, stage t+2 into (t+2)%3
  __shared__ bf16_t lA[3][BM * BK];   // 3 x 32 KB
  __shared__ bf16_t lB[3][BN * BK];   // 3 x 16 KB
  __shared__ float  lG[BM * 9];       // gates, padded stride 9 (bank spread)
  __shared__ float  lBe[E_SZ * BN];   // be tile: keeps loop free of global loads

  const int tid = threadIdx.x;
  const int w = tid >> 6, lane = tid & 63;

  // ---- XCD-locality remap (round 2: FETCH 533->97 MB) ----
  const int flat = blockIdx.x + (blockIdx.y << 3);  // gridDim.x == 8
  const int xcd = flat & 7, slot = flat >> 3;
  const int bt = (xcd << 2) + (slot & 3);  // b-tile 0..31
  const int ot = slot >> 2;                // o-tile 0..7
  const int b0 = bt * BM;
  const int o0 = ot * BN;

  const int wm = (w >> 1) * 64, wn = (w & 1) * 64;  // 4x2 wave grid, 64x64 per wave
  const int m16 = lane & 15, q = lane >> 4;

  // ---- prologue: gates + be into LDS (no global loads inside main loop!) ----
  {
    float4 g4 = ((const float4*)(gates + (size_t)b0 * 8))[tid];
    int gr = tid >> 1, gc = (tid & 1) * 4;
    lG[gr * 9 + gc + 0] = g4.x; lG[gr * 9 + gc + 1] = g4.y;
    lG[gr * 9 + gc + 2] = g4.z; lG[gr * 9 + gc + 3] = g4.w;
#pragma unroll
    for (int p = 0; p < 2; ++p) {
      int idx = tid + p * 512;
      lBe[idx] = be[(size_t)(idx >> 7) * O_SZ + o0 + (idx & 127)];
    }
  }

  // ---- per-lane staging constants ----
  // LDS dest is linear (wave base + lane*16); swizzle applied on the GLOBAL side:
  // phys 16B slot s at row r holds logical slot s^(r&7)  (read applies same XOR)
  const bf16_t* aptr[4]; int aoffL[4];
#pragma unroll
  for (int j = 0; j < 4; ++j) {
    int g0 = w * 64 + 512 * j;            // wave-uniform base granule
    int row = (g0 >> 3) + (lane >> 3);    // 8 granules (128B) per 64-col row
    int ls = (lane & 7) ^ (row & 7);      // logical slot this lane must fetch
    aptr[j] = xb + (size_t)(b0 + row) * D_SZ + ls * 8;
    aoffL[j] = g0 * 8;                    // LDS elem offset (granule*8 bf16)
  }
  const bf16_t* bptr[2]; int boffL[2];
#pragma unroll
  for (int j = 0; j < 2; ++j) {
    int g0 = w * 64 + 512 * j;
    int row = (g0 >> 3) + (lane >> 3);
    int ls = (lane & 7) ^ (row & 7);
    bptr[j] = wet + (size_t)(o0 + row) * D_SZ + ls * 8;
    boffL[j] = g0 * 8;
  }

  // ---- hoisted per-lane LDS read byte-offsets (loop-invariant) ----
  const int xk = m16 & 7;
  const int offA0 = (wm + m16) * 128 + ((q ^ xk) << 4);
  const int offA1 = (wm + m16) * 128 + (((4 | q) ^ xk) << 4);
  const int offB0 = (wn + m16) * 128 + ((q ^ xk) << 4);
  const int offB1 = (wn + m16) * 128 + (((4 | q) ^ xk) << 4);

#define STAGE(t_, buf_) do {                                                   \
    const int kk_ = ((t_) & 15) << 6;                                          \
    const size_t eo_ = (((size_t)((t_) >> 4)) << 20) + kk_;                    \
    _Pragma("unroll")                                                          \
    for (int js = 0; js < 4; ++js) gl16(aptr[js] + kk_, &lA[buf_][0] + aoffL[js]); \
    _Pragma("unroll")                                                          \
    for (int js = 0; js < 2; ++js) gl16(bptr[js] + eo_, &lB[buf_][0] + boffL[js]); \
  } while (0)

  f32x4 acc[4][4], outAcc[4][4];
#pragma unroll
  for (int i = 0; i < 4; ++i)
#pragma unroll
    for (int j = 0; j < 4; ++j) {
      acc[i][j] = f32x4{0.f, 0.f, 0.f, 0.f};
      outAcc[i][j] = f32x4{0.f, 0.f, 0.f, 0.f};
    }

  STAGE(0, 0);
  STAGE(1, 1);
  // drain own lG/lBe ds_writes so the first loop barrier publishes them
  asm volatile("s_waitcnt lgkmcnt(0)" ::: "memory");

  // one k-half phase: {4 B-reads + 4 A-reads -> 16 MFMA under setprio}.
  // Every ds_read is consumed by an MFMA in-phase, so compiler lgkm waits
  // drain all LDS reads before the next barrier -> single barrier per K-step.
#define HALF(cur_, OA_, OB_) do {                                              \
    const char* la_ = (const char*)(&lA[cur_][0]);                             \
    const char* lb_ = (const char*)(&lB[cur_][0]);                             \
    bf16x8 a_[4], b_[4];                                                       \
    _Pragma("unroll")                                                          \
    for (int j = 0; j < 4; ++j) b_[j] = *(const bf16x8*)(lb_ + (OB_) + j * 2048); \
    _Pragma("unroll")                                                          \
    for (int i = 0; i < 4; ++i) a_[i] = *(const bf16x8*)(la_ + (OA_) + i * 2048); \
    __builtin_amdgcn_s_setprio(1);                                             \
    _Pragma("unroll")                                                          \
    for (int i = 0; i < 4; ++i)                                                \
      _Pragma("unroll")                                                        \
      for (int j = 0; j < 4; ++j)                                              \
        acc[i][j] = __builtin_amdgcn_mfma_f32_16x16x32_bf16(                   \
            a_[i], b_[j], acc[i][j], 0, 0, 0);                                 \
    __builtin_amdgcn_s_setprio(0);                                             \
  } while (0)

  // parity stagger: even waves h0->h1, odd waves h1->h0. Breaks the post-
  // barrier lockstep so LDS-read and MFMA phases overlap ACROSS waves.
  // (k-half accumulate order swaps for odd waves: fp32 rounding-level only.)
#define BODY(cur_) do {                                                        \
    if ((w & 1) == 0) {                                                        \
      HALF(cur_, offA0, offB0);                                                \
      HALF(cur_, offA1, offB1);                                                \
    } else {                                                                   \
      HALF(cur_, offA1, offB1);                                                \
      HALF(cur_, offA0, offB0);                                                \
    }                                                                          \
  } while (0)

  // C layout: col = lane&15, row = q*4+reg  (dtype-independent on gfx950)
#define COMBINE(e_) do {                                                       \
    float bec_[4];                                                             \
    _Pragma("unroll")                                                          \
    for (int j = 0; j < 4; ++j) bec_[j] = lBe[(e_) * BN + wn + j * 16 + m16];  \
    _Pragma("unroll")                                                          \
    for (int i = 0; i < 4; ++i) {                                              \
      _Pragma("unroll")                                                        \
      for (int rg = 0; rg < 4; ++rg) {                                         \
        float gv = lG[(wm + i * 16 + q * 4 + rg) * 9 + (e_)];                  \
        _Pragma("unroll")                                                      \
        for (int j = 0; j < 4; ++j) {                                          \
          outAcc[i][j][rg] += gv * (acc[i][j][rg] + bec_[j]);                  \
          acc[i][j][rg] = 0.f;                                                 \
        }                                                                      \
      }                                                                        \
    }                                                                          \
  } while (0)

  // one K-step; cur_/nb_ are compile-time after manual unroll-3
#define STEP_S(t_, cur_, nb_) do {                                             \
    asm volatile("s_waitcnt vmcnt(6)" ::: "memory");                           \
    __builtin_amdgcn_s_barrier();                                              \
    asm volatile("" ::: "memory");                                             \
    STAGE((t_) + 2, nb_);                                                      \
    BODY(cur_);                                                                \
    if (((t_) & 15) == 15) COMBINE((t_) >> 4);                                 \
  } while (0)

#pragma unroll 1
  for (int t3 = 0; t3 < 126; t3 += 3) {
    STEP_S(t3 + 0, 0, 2);
    STEP_S(t3 + 1, 1, 0);
    STEP_S(t3 + 2, 2, 1);
  }
  // t = 126: no stage (tiles 0..127 all staged)
  asm volatile("s_waitcnt vmcnt(6)" ::: "memory");
  __builtin_amdgcn_s_barrier();
  asm volatile("" ::: "memory");
  BODY(0);
  // t = 127: final tile in buf 1
  asm volatile("s_waitcnt vmcnt(0)" ::: "memory");
  __builtin_amdgcn_s_barrier();
  asm volatile("" ::: "memory");
  BODY(1);
  COMBINE(7);

  // ---- epilogue: store combined output ----
#pragma unroll
  for (int i = 0; i < 4; ++i)
#pragma unroll
    for (int rg = 0; rg < 4; ++rg) {
      float* orow = out + (size_t)(b0 + wm + i * 16 + q * 4 + rg) * O_SZ
                    + o0 + wn + m16;
#pragma unroll
      for (int j = 0; j < 4; ++j) orow[j * 16] = outAcc[i][j][rg];
    }
}

extern "C" void kernel_launch(void* const* d_in, const int* in_sizes, int n_in,
                              void* d_out, int out_size, void* d_ws, size_t ws_size,
                              hipStream_t stream) {
  const float* x  = (const float*)d_in[0];
  const float* Wg = (const float*)d_in[1];
  const float* bg = (const float*)d_in[2];
  const float* We = (const float*)d_in[3];
  const float* be = (const float*)d_in[4];
  float* out = (float*)d_out;

  char* ws = (char*)d_ws;
  float*  gates = (float*)ws;                             // 256 KB
  bf16_t* xb    = (bf16_t*)(ws + (1 << 18));              // 16 MB
  bf16_t* wet   = (bf16_t*)(ws + (1 << 18) + (1 << 24));  // 16 MB

  prep_kernel<<<4096, 256, 0, stream>>>(x, Wg, bg, We, gates, xb, wet);
  moe_gemm<<<dim3(O_SZ / BN, B_SZ / BM), 512, 0, stream>>>(xb, wet, gates, be, out);
}

// Round 10
// 273.955 us; speedup vs baseline: 1.6444x; 1.6444x over previous
//
#include <hip/hip_runtime.h>
#include <hip/hip_bf16.h>
#include <stdint.h>

#define B_SZ 8192
#define D_SZ 1024
#define O_SZ 1024
#define E_SZ 8

#define BM 256
#define BN 128
#define BK 64
#define NT 128  // virtual K-steps: E_SZ * (D_SZ / BK)

typedef __bf16 bf16_t;
typedef __bf16 bf16x8 __attribute__((ext_vector_type(8)));
typedef __bf16 bf16x4 __attribute__((ext_vector_type(4)));
typedef float  f32x4  __attribute__((ext_vector_type(4)));

// ---------------- merged prep: gating+cvt (blocks 0..2047) | We transpose (2048..4095) ----------------
__global__ __launch_bounds__(256) void prep_kernel(
    const float* __restrict__ x, const float* __restrict__ Wg,
    const float* __restrict__ bg, const float* __restrict__ We,
    float* __restrict__ gates, bf16_t* __restrict__ xb,
    bf16_t* __restrict__ wet) {
  __shared__ float tile[64][65];
  const int bid = blockIdx.x;
  if (bid < 2048) {
    // ---- gating: softmax(x @ Wg + bg) fused with x fp32->bf16 ----
    const int w = threadIdx.x >> 6, lane = threadIdx.x & 63;
    const int b = bid * 4 + w;
    const float4* xr = (const float4*)(x + (size_t)b * D_SZ);
    bf16x4* xbr = (bf16x4*)(xb + (size_t)b * D_SZ);
    float acc[8];
#pragma unroll
    for (int e = 0; e < 8; ++e) acc[e] = 0.f;
#pragma unroll 1
    for (int it = 0; it < 4; ++it) {
      int d4 = it * 64 + lane;  // float4 index; d = d4*4
      float4 v = xr[d4];
      bf16x4 ob;
      ob[0] = (bf16_t)v.x; ob[1] = (bf16_t)v.y;
      ob[2] = (bf16_t)v.z; ob[3] = (bf16_t)v.w;
      xbr[d4] = ob;
      const float4* wr = (const float4*)(Wg + (size_t)d4 * 32);  // 4 rows x 8
      float xs[4] = {v.x, v.y, v.z, v.w};
#pragma unroll
      for (int rr = 0; rr < 4; ++rr) {
        float4 wa = wr[rr * 2], wb = wr[rr * 2 + 1];
        acc[0] += xs[rr] * wa.x; acc[1] += xs[rr] * wa.y;
        acc[2] += xs[rr] * wa.z; acc[3] += xs[rr] * wa.w;
        acc[4] += xs[rr] * wb.x; acc[5] += xs[rr] * wb.y;
        acc[6] += xs[rr] * wb.z; acc[7] += xs[rr] * wb.w;
      }
    }
#pragma unroll
    for (int off = 32; off >= 1; off >>= 1) {
#pragma unroll
      for (int e = 0; e < 8; ++e) acc[e] += __shfl_xor(acc[e], off, 64);
    }
    if (lane == 0) {
#pragma unroll
      for (int e = 0; e < 8; ++e) acc[e] += bg[e];
      float m = acc[0];
#pragma unroll
      for (int e = 1; e < 8; ++e) m = fmaxf(m, acc[e]);
      float s = 0.f, ex[8];
#pragma unroll
      for (int e = 0; e < 8; ++e) { ex[e] = __expf(acc[e] - m); s += ex[e]; }
      float inv = 1.0f / s;
      float* gr = gates + (size_t)b * 8;
#pragma unroll
      for (int e = 0; e < 8; ++e) gr[e] = ex[e] * inv;
    }
  } else {
    // ---- We [E,D,O] fp32 -> WeT [E,O,D] bf16 ----
    const int bt = bid - 2048;
    const int e = bt >> 8;
    const int d0 = ((bt >> 4) & 15) * 64, o0 = (bt & 15) * 64;
    const int tx = threadIdx.x & 63, ty = threadIdx.x >> 6;
    const float* src = We + (size_t)e * D_SZ * O_SZ;
#pragma unroll
    for (int i = 0; i < 16; ++i) {
      int d = ty + i * 4;
      tile[d][tx] = src[(size_t)(d0 + d) * O_SZ + o0 + tx];
    }
    __syncthreads();
    bf16_t* dst = wet + (size_t)e * O_SZ * D_SZ;
#pragma unroll
    for (int i = 0; i < 16; ++i) {
      int o = ty + i * 4;
      dst[(size_t)(o0 + o) * D_SZ + d0 + tx] = (bf16_t)tile[tx][o];
    }
  }
}

// ---------------- fused expert GEMM + gate combine (R3 + 2-phase barrier brackets) ----------------
// R3 proven structure (ring-3 LDS, counted vmcnt(6), XOR swizzle, hoisted LDS
// offsets) + m201-style phase brackets: each K-step = two phases
//   {8 ds_reads + 3 staging gloads} -> barrier -> lgkmcnt(0) -> setprio(1)
//   16 MFMA setprio(0) -> barrier
// Correctness carried by the step-top vmcnt(6)+barrier (unchanged from R3);
// the added barriers only align waves so read clusters of one phase overlap
// MFMA clusters of the other across the CU (T3 role-split; T5 then pays).
// NO divergent branches (R9 lesson), NO geometry change (R4/R5 lesson).
__device__ __forceinline__ void gl16(const bf16_t* g, const bf16_t* l) {
  __builtin_amdgcn_global_load_lds(
      (const __attribute__((address_space(1))) void*)g,
      (__attribute__((address_space(3))) void*)l, 16, 0, 0);
}

__global__ __launch_bounds__(512, 2) void moe_gemm(
    const bf16_t* __restrict__ xb,    // [B, D] bf16
    const bf16_t* __restrict__ wet,   // [E, O, D] bf16
    const float* __restrict__ gates,  // [B, E]
    const float* __restrict__ be,     // [E, O]
    float* __restrict__ out)          // [B, O]
{
  // ring-3 buffers: compute t from buf t%3, stage t+2 into (t+2)%3
  __shared__ bf16_t lA[3][BM * BK];   // 3 x 32 KB
  __shared__ bf16_t lB[3][BN * BK];   // 3 x 16 KB
  __shared__ float  lG[BM * 9];       // gates, padded stride 9 (bank spread)
  __shared__ float  lBe[E_SZ * BN];   // be tile: keeps loop free of global loads

  const int tid = threadIdx.x;
  const int w = tid >> 6, lane = tid & 63;

  // ---- XCD-locality remap (round 2: FETCH 533->97 MB) ----
  const int flat = blockIdx.x + (blockIdx.y << 3);  // gridDim.x == 8
  const int xcd = flat & 7, slot = flat >> 3;
  const int bt = (xcd << 2) + (slot & 3);  // b-tile 0..31
  const int ot = slot >> 2;                // o-tile 0..7
  const int b0 = bt * BM;
  const int o0 = ot * BN;

  const int wm = (w >> 1) * 64, wn = (w & 1) * 64;  // 4x2 wave grid, 64x64 per wave
  const int m16 = lane & 15, q = lane >> 4;

  // ---- prologue: gates + be into LDS (no global loads inside main loop!) ----
  {
    float4 g4 = ((const float4*)(gates + (size_t)b0 * 8))[tid];
    int gr = tid >> 1, gc = (tid & 1) * 4;
    lG[gr * 9 + gc + 0] = g4.x; lG[gr * 9 + gc + 1] = g4.y;
    lG[gr * 9 + gc + 2] = g4.z; lG[gr * 9 + gc + 3] = g4.w;
#pragma unroll
    for (int p = 0; p < 2; ++p) {
      int idx = tid + p * 512;
      lBe[idx] = be[(size_t)(idx >> 7) * O_SZ + o0 + (idx & 127)];
    }
  }

  // ---- per-lane staging constants ----
  // LDS dest is linear (wave base + lane*16); swizzle applied on the GLOBAL side:
  // phys 16B slot s at row r holds logical slot s^(r&7)  (read applies same XOR)
  const bf16_t* aptr[4]; int aoffL[4];
#pragma unroll
  for (int j = 0; j < 4; ++j) {
    int g0 = w * 64 + 512 * j;            // wave-uniform base granule
    int row = (g0 >> 3) + (lane >> 3);    // 8 granules (128B) per 64-col row
    int ls = (lane & 7) ^ (row & 7);      // logical slot this lane must fetch
    aptr[j] = xb + (size_t)(b0 + row) * D_SZ + ls * 8;
    aoffL[j] = g0 * 8;                    // LDS elem offset (granule*8 bf16)
  }
  const bf16_t* bptr[2]; int boffL[2];
#pragma unroll
  for (int j = 0; j < 2; ++j) {
    int g0 = w * 64 + 512 * j;
    int row = (g0 >> 3) + (lane >> 3);
    int ls = (lane & 7) ^ (row & 7);
    bptr[j] = wet + (size_t)(o0 + row) * D_SZ + ls * 8;
    boffL[j] = g0 * 8;
  }

  // ---- hoisted per-lane LDS read byte-offsets (loop-invariant) ----
  const int xk = m16 & 7;
  const int offA0 = (wm + m16) * 128 + ((q ^ xk) << 4);
  const int offA1 = (wm + m16) * 128 + (((4 | q) ^ xk) << 4);
  const int offB0 = (wn + m16) * 128 + ((q ^ xk) << 4);
  const int offB1 = (wn + m16) * 128 + (((4 | q) ^ xk) << 4);

  // staging split 3+3 across the two phases; 6 loads/step total (vmcnt invariant)
#define STAGE_H0(t_, buf_) do {                                                \
    const int kk_ = ((t_) & 15) << 6;                                          \
    const size_t eo_ = (((size_t)((t_) >> 4)) << 20) + kk_;                    \
    gl16(aptr[0] + kk_, &lA[buf_][0] + aoffL[0]);                              \
    gl16(aptr[1] + kk_, &lA[buf_][0] + aoffL[1]);                              \
    gl16(bptr[0] + eo_, &lB[buf_][0] + boffL[0]);                              \
  } while (0)
#define STAGE_H1(t_, buf_) do {                                                \
    const int kk_ = ((t_) & 15) << 6;                                          \
    const size_t eo_ = (((size_t)((t_) >> 4)) << 20) + kk_;                    \
    gl16(aptr[2] + kk_, &lA[buf_][0] + aoffL[2]);                              \
    gl16(aptr[3] + kk_, &lA[buf_][0] + aoffL[3]);                              \
    gl16(bptr[1] + eo_, &lB[buf_][0] + boffL[1]);                              \
  } while (0)
#define STAGE_FULL(t_, buf_) do { STAGE_H0(t_, buf_); STAGE_H1(t_, buf_); } while (0)

  f32x4 acc[4][4], outAcc[4][4];
#pragma unroll
  for (int i = 0; i < 4; ++i)
#pragma unroll
    for (int j = 0; j < 4; ++j) {
      acc[i][j] = f32x4{0.f, 0.f, 0.f, 0.f};
      outAcc[i][j] = f32x4{0.f, 0.f, 0.f, 0.f};
    }

  STAGE_FULL(0, 0);
  STAGE_FULL(1, 1);
  // drain own lG/lBe ds_writes so the first loop barrier publishes them
  asm volatile("s_waitcnt lgkmcnt(0)" ::: "memory");

  // one phase: {8 ds_reads + optional 3-gload stage} | barrier | lgkm0 |
  // setprio1 16 MFMA setprio0. Trailing barrier provided by caller sequence.
#define PHASE(cur_, OA_, OB_, STG_) do {                                       \
    const char* la_ = (const char*)(&lA[cur_][0]);                             \
    const char* lb_ = (const char*)(&lB[cur_][0]);                             \
    bf16x8 a_[4], b_[4];                                                       \
    _Pragma("unroll")                                                          \
    for (int j = 0; j < 4; ++j) b_[j] = *(const bf16x8*)(lb_ + (OB_) + j * 2048); \
    _Pragma("unroll")                                                          \
    for (int i = 0; i < 4; ++i) a_[i] = *(const bf16x8*)(la_ + (OA_) + i * 2048); \
    STG_;                                                                      \
    __builtin_amdgcn_s_barrier();                                              \
    asm volatile("s_waitcnt lgkmcnt(0)" ::: "memory");                         \
    __builtin_amdgcn_sched_barrier(0);                                         \
    __builtin_amdgcn_s_setprio(1);                                             \
    _Pragma("unroll")                                                          \
    for (int i = 0; i < 4; ++i)                                                \
      _Pragma("unroll")                                                        \
      for (int j = 0; j < 4; ++j)                                              \
        acc[i][j] = __builtin_amdgcn_mfma_f32_16x16x32_bf16(                   \
            a_[i], b_[j], acc[i][j], 0, 0, 0);                                 \
    __builtin_amdgcn_s_setprio(0);                                             \
  } while (0)

  // C layout: col = lane&15, row = q*4+reg  (dtype-independent on gfx950)
#define COMBINE(e_) do {                                                       \
    float bec_[4];                                                             \
    _Pragma("unroll")                                                          \
    for (int j = 0; j < 4; ++j) bec_[j] = lBe[(e_) * BN + wn + j * 16 + m16];  \
    _Pragma("unroll")                                                          \
    for (int i = 0; i < 4; ++i) {                                              \
      _Pragma("unroll")                                                        \
      for (int rg = 0; rg < 4; ++rg) {                                         \
        float gv = lG[(wm + i * 16 + q * 4 + rg) * 9 + (e_)];                  \
        _Pragma("unroll")                                                      \
        for (int j = 0; j < 4; ++j) {                                          \
          outAcc[i][j][rg] += gv * (acc[i][j][rg] + bec_[j]);                  \
          acc[i][j][rg] = 0.f;                                                 \
        }                                                                      \
      }                                                                        \
    }                                                                          \
  } while (0)

  // one K-step: top vmcnt(6)+barrier (correctness, from R3), then 2 bracketed
  // phases. Barriers/step: top + pre-MFMA(h0) + post(h0) + pre-MFMA(h1); the
  // post-h1 barrier is the next step's top. All waves uniform (no divergence).
#define STEP_S(t_, cur_, nb_) do {                                             \
    asm volatile("s_waitcnt vmcnt(6)" ::: "memory");                           \
    __builtin_amdgcn_s_barrier();                                              \
    asm volatile("" ::: "memory");                                             \
    PHASE(cur_, offA0, offB0, STAGE_H0((t_) + 2, nb_));                        \
    __builtin_amdgcn_s_barrier();                                              \
    PHASE(cur_, offA1, offB1, STAGE_H1((t_) + 2, nb_));                        \
    if (((t_) & 15) == 15) COMBINE((t_) >> 4);                                 \
  } while (0)

#pragma unroll 1
  for (int t3 = 0; t3 < 126; t3 += 3) {
    STEP_S(t3 + 0, 0, 2);
    STEP_S(t3 + 1, 1, 0);
    STEP_S(t3 + 2, 2, 1);
  }
  // t = 126: no stage (tiles 0..127 all staged)
  asm volatile("s_waitcnt vmcnt(6)" ::: "memory");
  __builtin_amdgcn_s_barrier();
  asm volatile("" ::: "memory");
  PHASE(0, offA0, offB0, (void)0);
  __builtin_amdgcn_s_barrier();
  PHASE(0, offA1, offB1, (void)0);
  // t = 127: final tile in buf 1
  asm volatile("s_waitcnt vmcnt(0)" ::: "memory");
  __builtin_amdgcn_s_barrier();
  asm volatile("" ::: "memory");
  PHASE(1, offA0, offB0, (void)0);
  __builtin_amdgcn_s_barrier();
  PHASE(1, offA1, offB1, (void)0);
  COMBINE(7);

  // ---- epilogue: store combined output ----
#pragma unroll
  for (int i = 0; i < 4; ++i)
#pragma unroll
    for (int rg = 0; rg < 4; ++rg) {
      float* orow = out + (size_t)(b0 + wm + i * 16 + q * 4 + rg) * O_SZ
                    + o0 + wn + m16;
#pragma unroll
      for (int j = 0; j < 4; ++j) orow[j * 16] = outAcc[i][j][rg];
    }
}

extern "C" void kernel_launch(void* const* d_in, const int* in_sizes, int n_in,
                              void* d_out, int out_size, void* d_ws, size_t ws_size,
                              hipStream_t stream) {
  const float* x  = (const float*)d_in[0];
  const float* Wg = (const float*)d_in[1];
  const float* bg = (const float*)d_in[2];
  const float* We = (const float*)d_in[3];
  const float* be = (const float*)d_in[4];
  float* out = (float*)d_out;

  char* ws = (char*)d_ws;
  float*  gates = (float*)ws;                             // 256 KB
  bf16_t* xb    = (bf16_t*)(ws + (1 << 18));              // 16 MB
  bf16_t* wet   = (bf16_t*)(ws + (1 << 18) + (1 << 24));  // 16 MB

  prep_kernel<<<4096, 256, 0, stream>>>(x, Wg, bg, We, gates, xb, wet);
  moe_gemm<<<dim3(O_SZ / BN, B_SZ / BM), 512, 0, stream>>>(xb, wet, gates, be, out);
}